// Round 3
// baseline (899.779 us; speedup 1.0000x reference)
//
#include <hip/hip_runtime.h>
#include <hip/hip_bf16.h>

#define B_ 32
#define P_ 512
#define Q_ 64
#define E_ 300
#define KP 320          // E padded to multiple of 32 for MFMA K-steps
#define H_ 256
#define HH_ 128
#define NEG (-1e7f)
#define BP (B_*P_)
#define BQ (B_*Q_)

typedef __attribute__((ext_vector_type(8))) short bf16x8;
typedef __attribute__((ext_vector_type(4))) float f32x4;

// ---- static device workspace (fully rewritten every call) ----
__device__ __hip_bfloat16 g_ep[BP][KP];      // gathered passage embeddings (bf16)
__device__ __hip_bfloat16 g_eq[BQ][KP];      // gathered question embeddings
__device__ __hip_bfloat16 g_wp[768][KP];     // combined passage wih
__device__ __hip_bfloat16 g_wq[768][KP];     // combined question wih
__device__ float g_biasp[768];               // bih (+ bhh for r,z gates)
__device__ float g_biasq[768];
__device__ float g_xtp[2L*P_*B_*384];        // passage x-proj, [dir][t][b][384]
__device__ float g_xtq[2L*Q_*B_*384];        // question x-proj
__device__ float g_penc[BP*H_];              // BiGRU passage encodings (f32)
__device__ float g_qenc[BQ*H_];              // BiGRU question encodings

struct PrepArgs { const float* wih[4]; const float* bih[4]; const float* bhh[4]; };
struct GruArgs  { const float* whh[4]; const float* bhh[4]; const int* ptok; const int* qtok; };

// ---------------- weight repack + bias fold ----------------
__global__ __launch_bounds__(64) void k_prepw(PrepArgs pa) {
    int r = blockIdx.x;                 // 0..1535
    int pq = r / 768, col = r % 768;
    int dir = col / 384, within = col % 384, gate = within / 128;
    int idx = pq * 2 + dir;             // {p_f,p_b,q_f,q_b}
    const float* wsrc = pa.wih[idx] + within * E_;
    __hip_bfloat16* dst = pq ? g_wq[col] : g_wp[col];
    for (int c = threadIdx.x; c < KP; c += 64)
        dst[c] = __float2bfloat16(c < E_ ? wsrc[c] : 0.f);
    if (threadIdx.x == 0) {
        float bsum = pa.bih[idx][within] + (gate < 2 ? pa.bhh[idx][within] : 0.f);
        (pq ? g_biasq : g_biasp)[col] = bsum;
    }
}

// ---------------- embedding gather (f32 -> bf16, K padded) ----------------
__global__ __launch_bounds__(256) void k_gather(const int* pass, const int* ques, const float* emb) {
    int row = blockIdx.x * 4 + (threadIdx.x >> 6);
    int lane = threadIdx.x & 63;
    const int* tsrc; __hip_bfloat16* dst; int r;
    if (row < BP) { r = row; tsrc = pass; dst = &g_ep[r][0]; }
    else          { r = row - BP; tsrc = ques; dst = &g_eq[r][0]; }
    int tk = tsrc[r];
    const float* src = emb + (long)tk * E_;
    #pragma unroll
    for (int i = 0; i < 5; i++) {
        int c = i * 64 + lane;
        float v = (c < E_) ? src[c] : 0.f;
        dst[c] = __float2bfloat16(v);
    }
}

// ---------------- input-projection GEMM: x_t[dir][t][b][384] = ep @ wih^T + bias ----------------
__global__ __launch_bounds__(256) void k_gemm(int isQ) {
    const __hip_bfloat16* A  = isQ ? &g_eq[0][0] : &g_ep[0][0];
    const __hip_bfloat16* Bw = isQ ? &g_wq[0][0] : &g_wp[0][0];
    const float* bias = isQ ? g_biasq : g_biasp;
    float* Xt = isQ ? g_xtq : g_xtp;
    const int T = isQ ? Q_ : P_;
    const int tsh = isQ ? 6 : 9;        // log2(T)
    __shared__ __hip_bfloat16 As[128][40];
    __shared__ __hip_bfloat16 Bs[128][40];
    int m0 = blockIdx.x * 128, n0 = blockIdx.y * 128;
    int tid = threadIdx.x, lane = tid & 63, w = tid >> 6;
    int wm = (w & 1) * 64, wn = (w >> 1) * 64;
    f32x4 acc[4][4] = {};
    int lr = tid >> 1, lc = (tid & 1) * 16;
    for (int kt = 0; kt < KP; kt += 32) {
        *(bf16x8*)&As[lr][lc]   = *(const bf16x8*)&A [(m0 + lr) * KP + kt + lc];
        *(bf16x8*)&As[lr][lc+8] = *(const bf16x8*)&A [(m0 + lr) * KP + kt + lc + 8];
        *(bf16x8*)&Bs[lr][lc]   = *(const bf16x8*)&Bw[(n0 + lr) * KP + kt + lc];
        *(bf16x8*)&Bs[lr][lc+8] = *(const bf16x8*)&Bw[(n0 + lr) * KP + kt + lc + 8];
        __syncthreads();
        int kb = (lane >> 4) * 8, l15 = lane & 15;
        bf16x8 af[4], bfr[4];
        #pragma unroll
        for (int i = 0; i < 4; i++) af[i]  = *(bf16x8*)&As[wm + i*16 + l15][kb];
        #pragma unroll
        for (int j = 0; j < 4; j++) bfr[j] = *(bf16x8*)&Bs[wn + j*16 + l15][kb];
        #pragma unroll
        for (int i = 0; i < 4; i++)
            #pragma unroll
            for (int j = 0; j < 4; j++)
                acc[i][j] = __builtin_amdgcn_mfma_f32_16x16x32_bf16(af[i], bfr[j], acc[i][j], 0, 0, 0);
        __syncthreads();
    }
    int l15 = lane & 15, lr4 = (lane >> 4) * 4;
    #pragma unroll
    for (int jj = 0; jj < 4; jj++) {
        int n = n0 + wn + jj * 16 + l15;
        float bn = bias[n];
        int dirn = n >= 384;
        int col = n - dirn * 384;
        float* Cx = Xt + (long)dirn * T * B_ * 384;
        #pragma unroll
        for (int i = 0; i < 4; i++) {
            int mb = m0 + wm + i * 16 + lr4;
            #pragma unroll
            for (int q = 0; q < 4; q++) {
                int m = mb + q;
                int b = m >> tsh, t = m & (T - 1);
                Cx[((long)t * B_ + b) * 384 + col] = acc[i][jj][q] + bn;
            }
        }
    }
}

// ---------------- GRU recurrence: MFMA over 16 chains per block ----------------
// 8 blocks x 512 threads (8 waves). Block handles 16 chains (one dir, 16 batches).
// Wave w owns hidden cols j=16w+(lane&15) for all 3 gates (N-tiles {w,w+8,w+16}),
// so r/z/n preacts align per lane/reg and h_old stays in-lane.
__global__ __launch_bounds__(512, 1) void k_gru(GruArgs ga) {
    int blk = blockIdx.x;               // 0..7
    int isQ = blk >> 2;
    int dir = (blk >> 1) & 1;
    int bbase = (blk & 1) * 16;
    const int T = isQ ? Q_ : P_;
    const float* xt = (isQ ? g_xtq : g_xtp) + (long)dir * T * B_ * 384;
    const int* tok = isQ ? ga.qtok : ga.ptok;
    float* outp = isQ ? g_qenc : g_penc;
    const float* whh = ga.whh[isQ * 2 + dir];
    const float* bhh = ga.bhh[isQ * 2 + dir];
    int tid = threadIdx.x, w = tid >> 6, l = tid & 63;
    int l15 = l & 15, lg = l >> 4;
    int j = w * 16 + l15;               // hidden col owned (0..127)
    int m0 = lg * 4;                    // chain rows m0..m0+3

    // B-fragments (whh resident as MFMA operands): bw[gate][kstep]
    bf16x8 bw[3][4];
    #pragma unroll
    for (int g = 0; g < 3; g++)
        #pragma unroll
        for (int ks = 0; ks < 4; ks++) {
            const float* src = whh + (long)(g * 128 + j) * HH_ + ks * 32 + lg * 8;
            union { bf16x8 v; __hip_bfloat16 h[8]; } u;
            #pragma unroll
            for (int e = 0; e < 8; e++) u.h[e] = __float2bfloat16(src[e]);
            bw[g][ks] = u.v;
        }
    float bnn = bhh[256 + j];           // n-gate hidden bias (applied before r-multiply)

    __shared__ char hb[2][4096];        // h as bf16 [16][128], XOR-swizzled, dbuf

    f32x4 hold = {0.f, 0.f, 0.f, 0.f};
    bf16x8 af[4] = {};                  // h_{-1} = 0
    int cur = 0;

    // 2-deep x/token prefetch pipeline (covers L2/L3 latency)
    float xA[3][4], xB[3][4];
    int tkA[4], tkB[4];
    {
        int t0 = dir ? T - 1 : 0;
        int s1 = (T > 1) ? 1 : 0;
        int t1 = dir ? T - 1 - s1 : s1;
        #pragma unroll
        for (int g = 0; g < 3; g++)
            #pragma unroll
            for (int q = 0; q < 4; q++) {
                xA[g][q] = xt[((long)t0 * B_ + bbase + m0 + q) * 384 + g * 128 + j];
                xB[g][q] = xt[((long)t1 * B_ + bbase + m0 + q) * 384 + g * 128 + j];
            }
        #pragma unroll
        for (int q = 0; q < 4; q++) {
            tkA[q] = tok[(bbase + m0 + q) * T + t0];
            tkB[q] = tok[(bbase + m0 + q) * T + t1];
        }
    }

    for (int st = 0; st < T; st++) {
        int t = dir ? T - 1 - st : st;
        int s2 = (st + 2 < T) ? st + 2 : T - 1;
        int t2 = dir ? T - 1 - s2 : s2;

        f32x4 acc0 = {}, acc1 = {}, acc2 = {};
        #pragma unroll
        for (int ks = 0; ks < 4; ks++) {
            acc0 = __builtin_amdgcn_mfma_f32_16x16x32_bf16(af[ks], bw[0][ks], acc0, 0, 0, 0);
            acc1 = __builtin_amdgcn_mfma_f32_16x16x32_bf16(af[ks], bw[1][ks], acc1, 0, 0, 0);
            acc2 = __builtin_amdgcn_mfma_f32_16x16x32_bf16(af[ks], bw[2][ks], acc2, 0, 0, 0);
        }

        // prefetch st+2 (issue early, consume next-next iter)
        float xC[3][4]; int tkC[4];
        #pragma unroll
        for (int g = 0; g < 3; g++)
            #pragma unroll
            for (int q = 0; q < 4; q++)
                xC[g][q] = xt[((long)t2 * B_ + bbase + m0 + q) * 384 + g * 128 + j];
        #pragma unroll
        for (int q = 0; q < 4; q++) tkC[q] = tok[(bbase + m0 + q) * T + t2];

        // gates + output
        f32x4 hnew;
        #pragma unroll
        for (int q = 0; q < 4; q++) {
            float pr = acc0[q] + xA[0][q];
            float pz = acc1[q] + xA[1][q];
            float pn = acc2[q] + bnn;
            float rg = 1.f / (1.f + __expf(-pr));
            float zg = 1.f / (1.f + __expf(-pz));
            float ta = xA[2][q] + rg * pn;
            ta = fminf(fmaxf(ta, -15.f), 15.f);
            float e2 = __expf(2.f * ta);
            float nn = (e2 - 1.f) / (e2 + 1.f);
            float hv = hold[q];
            float hm = tkA[q] ? ((1.f - zg) * nn + zg * hv) : hv;
            hnew[q] = hm;
            outp[((long)(bbase + m0 + q) * T + t) * H_ + dir * HH_ + j] = tkA[q] ? hm : 0.f;
        }
        hold = hnew;

        // write h_t to LDS (XOR-swizzled bf16), barrier, read next A-frags
        char* wb = hb[cur ^ 1];
        #pragma unroll
        for (int q = 0; q < 4; q++) {
            int m = m0 + q;
            int ba = m * 256 + ((j * 2) ^ ((m & 7) << 4));
            *(__hip_bfloat16*)(wb + ba) = __float2bfloat16(hnew[q]);
        }
        __syncthreads();
        const char* rb = hb[cur ^ 1];
        #pragma unroll
        for (int ks = 0; ks < 4; ks++)
            af[ks] = *(const bf16x8*)(rb + l15 * 256 + ((ks * 64 + lg * 16) ^ ((l15 & 7) << 4)));
        cur ^= 1;

        // rotate prefetch pipeline
        #pragma unroll
        for (int g = 0; g < 3; g++)
            #pragma unroll
            for (int q = 0; q < 4; q++) { xA[g][q] = xB[g][q]; xB[g][q] = xC[g][q]; }
        #pragma unroll
        for (int q = 0; q < 4; q++) { tkA[q] = tkB[q]; tkB[q] = tkC[q]; }
    }
}

// ---------------- fused attention + output heads ----------------
#define QPAD 260
__global__ __launch_bounds__(256) void k_attn(const int* pass, const int* ques,
        const float* attn_w, const float* attn_b, const float* start_w,
        const float* start_b, const float* end_w, const float* end_b, float* out) {
    __shared__ float qs[Q_][QPAD];
    __shared__ float pw3[H_];
    __shared__ float lrow[Q_];
    __shared__ float probs[Q_];
    __shared__ float s2v[Q_];
    __shared__ int   qmS[Q_];
    __shared__ float red[4], redA[4], redB[4];
    __shared__ float awpart[4][QPAD];
    int b = blockIdx.x >> 6, pch = blockIdx.x & 63;
    int tid = threadIdx.x, lane = tid & 63, wid = tid >> 6;
    for (int i = tid; i < Q_ * H_; i += 256) {
        int q = i >> 8, h = i & 255;
        qs[q][h] = g_qenc[(long)(b * Q_ + q) * H_ + h];
    }
    if (tid < Q_) qmS[tid] = (ques[b * Q_ + tid] != 0);
    __syncthreads();
    int q4 = tid >> 2, part = tid & 3;
    {   // s2[q] = dot(qenc[q], w2)
        float p2 = 0.f;
        #pragma unroll 8
        for (int i = 0; i < 64; i++)
            p2 += qs[q4][part * 64 + i] * attn_w[256 + part * 64 + i];
        p2 += __shfl_xor(p2, 1);
        p2 += __shfl_xor(p2, 2);
        if (part == 0) s2v[q4] = p2;
    }
    __syncthreads();
    float ab = attn_b[0], sb = start_b[0], ebv = end_b[0];
    for (int pi = 0; pi < 8; pi++) {
        int p = pch * 8 + pi;
        float pv = g_penc[(long)(b * P_ + p) * H_ + tid];
        pw3[tid] = pv * attn_w[512 + tid];
        float r1 = pv * attn_w[tid];
        #pragma unroll
        for (int s = 1; s < 64; s <<= 1) r1 += __shfl_xor(r1, s);
        if (lane == 0) red[wid] = r1;
        __syncthreads();                                  // (A) pw3 + red
        float s1 = red[0] + red[1] + red[2] + red[3];
        float acc = 0.f;
        #pragma unroll
        for (int i = 0; i < 16; i++) {
            float4 qv = *(const float4*)&qs[q4][part * 64 + i * 4];
            float4 wv = *(const float4*)&pw3[part * 64 + i * 4];
            acc += qv.x * wv.x + qv.y * wv.y + qv.z * wv.z + qv.w * wv.w;
        }
        acc += __shfl_xor(acc, 1);
        acc += __shfl_xor(acc, 2);
        if (part == 0) lrow[q4] = qmS[q4] ? (s1 + s2v[q4] + acc + ab) : NEG;
        __syncthreads();                                  // (B) lrow
        if (tid < 64) {
            float v = lrow[tid];
            float m = v;
            #pragma unroll
            for (int s = 1; s < 64; s <<= 1) m = fmaxf(m, __shfl_xor(m, s));
            float e = __expf(v - m);
            float ss = e;
            #pragma unroll
            for (int s = 1; s < 64; s <<= 1) ss += __shfl_xor(ss, s);
            probs[tid] = e / ss;
        }
        __syncthreads();                                  // (C) probs
        float4 aw4 = {0.f, 0.f, 0.f, 0.f};
        #pragma unroll
        for (int qq = 0; qq < 16; qq++) {
            int q = wid * 16 + qq;
            float pq = probs[q];
            float4 qv = *(const float4*)&qs[q][lane * 4];
            aw4.x = fmaf(pq, qv.x, aw4.x);
            aw4.y = fmaf(pq, qv.y, aw4.y);
            aw4.z = fmaf(pq, qv.z, aw4.z);
            aw4.w = fmaf(pq, qv.w, aw4.w);
        }
        *(float4*)&awpart[wid][lane * 4] = aw4;
        __syncthreads();                                  // (D0) awpart
        float aw = awpart[0][tid] + awpart[1][tid] + awpart[2][tid] + awpart[3][tid];
        float spv = pv * start_w[tid] + aw * start_w[256 + tid] + pv * aw * start_w[512 + tid];
        float epv = pv * end_w[tid]   + aw * end_w[256 + tid]   + pv * aw * end_w[512 + tid];
        #pragma unroll
        for (int s = 1; s < 64; s <<= 1) {
            spv += __shfl_xor(spv, s);
            epv += __shfl_xor(epv, s);
        }
        if (lane == 0) { redA[wid] = spv; redB[wid] = epv; }
        __syncthreads();                                  // (D) redA/B
        if (tid == 0) {
            int pm = (pass[b * P_ + p] != 0);
            float sv = redA[0] + redA[1] + redA[2] + redA[3] + sb;
            float ev = redB[0] + redB[1] + redB[2] + redB[3] + ebv;
            out[b * P_ + p]       = pm ? sv : NEG;
            out[BP + b * P_ + p]  = pm ? ev : NEG;
        }
        __syncthreads();                                  // (E) end of row
    }
}

// ---------------- log_softmax over P per (batch, start/end) ----------------
__global__ __launch_bounds__(256) void k_lsm(float* out) {
    int b = blockIdx.x >> 1, which = blockIdx.x & 1;
    const float* src = out + which * BP + b * P_;
    int tid = threadIdx.x;
    float v0 = src[tid], v1 = src[tid + 256];
    __shared__ float red[4];
    float m = fmaxf(v0, v1);
    #pragma unroll
    for (int s = 1; s < 64; s <<= 1) m = fmaxf(m, __shfl_xor(m, s));
    if ((tid & 63) == 0) red[tid >> 6] = m;
    __syncthreads();
    m = fmaxf(fmaxf(red[0], red[1]), fmaxf(red[2], red[3]));
    __syncthreads();
    float ss = __expf(v0 - m) + __expf(v1 - m);
    #pragma unroll
    for (int s = 1; s < 64; s <<= 1) ss += __shfl_xor(ss, s);
    if ((tid & 63) == 0) red[tid >> 6] = ss;
    __syncthreads();
    float lse = m + logf(red[0] + red[1] + red[2] + red[3]);
    float* dst = out + (2 + which) * BP + b * P_;
    dst[tid] = v0 - lse;
    dst[tid + 256] = v1 - lse;
}

extern "C" void kernel_launch(void* const* d_in, const int* in_sizes, int n_in,
                              void* d_out, int out_size, void* d_ws, size_t ws_size,
                              hipStream_t stream) {
    const int* pass = (const int*)d_in[0];
    const int* ques = (const int*)d_in[1];
    const float* emb = (const float*)d_in[2];
    PrepArgs pa; GruArgs ga;
    const int base[4] = {3, 7, 11, 15};   // p_f, p_b, q_f, q_b blocks of 4 inputs
    for (int i = 0; i < 4; i++) {
        pa.wih[i] = (const float*)d_in[base[i] + 0];
        ga.whh[i] = (const float*)d_in[base[i] + 1];
        pa.bih[i] = (const float*)d_in[base[i] + 2];
        pa.bhh[i] = (const float*)d_in[base[i] + 3];
        ga.bhh[i] = pa.bhh[i];
    }
    ga.ptok = pass; ga.qtok = ques;
    const float* attn_w  = (const float*)d_in[19];
    const float* attn_b  = (const float*)d_in[20];
    const float* start_w = (const float*)d_in[21];
    const float* start_b = (const float*)d_in[22];
    const float* end_w   = (const float*)d_in[23];
    const float* end_b   = (const float*)d_in[24];
    float* out = (float*)d_out;

    k_prepw <<<dim3(1536), dim3(64), 0, stream>>>(pa);
    k_gather<<<dim3((BP + BQ) / 4), dim3(256), 0, stream>>>(pass, ques, emb);
    k_gemm  <<<dim3(BP / 128, 6), dim3(256), 0, stream>>>(0);
    k_gemm  <<<dim3(BQ / 128, 6), dim3(256), 0, stream>>>(1);
    k_gru   <<<dim3(8), dim3(512), 0, stream>>>(ga);
    k_attn  <<<dim3(B_ * 64), dim3(256), 0, stream>>>(pass, ques, attn_w, attn_b,
                                                      start_w, start_b, end_w, end_b, out);
    k_lsm   <<<dim3(64), dim3(256), 0, stream>>>(out);
}

// Round 4
// 841.594 us; speedup vs baseline: 1.0691x; 1.0691x over previous
//
#include <hip/hip_runtime.h>
#include <hip/hip_bf16.h>

#define B_ 32
#define P_ 512
#define Q_ 64
#define E_ 300
#define KP 320          // E padded to multiple of 32 for MFMA K-steps
#define H_ 256
#define HH_ 128
#define NEG (-1e7f)
#define BP (B_*P_)
#define BQ (B_*Q_)

typedef __attribute__((ext_vector_type(8))) short bf16x8;
typedef __attribute__((ext_vector_type(4))) float f32x4;

// ---- static device workspace (fully rewritten every call) ----
__device__ __hip_bfloat16 g_ep[BP][KP];      // gathered passage embeddings (bf16)
__device__ __hip_bfloat16 g_eq[BQ][KP];      // gathered question embeddings
__device__ __hip_bfloat16 g_wp[768][KP];     // combined passage wih
__device__ __hip_bfloat16 g_wq[768][KP];     // combined question wih
__device__ float g_biasp[768];               // bih (+ bhh for r,z gates)
__device__ float g_biasq[768];
__device__ float g_biasn[4][HH_];            // bhh n-gate bias per weight set
__device__ short g_whhrep[4*12*512*8];       // whh repacked in MFMA B-frag order
__device__ float g_xtp[2L*P_*B_*384];        // passage x-proj, [dir][t][b][384]
__device__ float g_xtq[2L*Q_*B_*384];        // question x-proj
__device__ float g_penc[BP*H_];              // BiGRU passage encodings (f32)
__device__ float g_qenc[BQ*H_];              // BiGRU question encodings

struct PrepArgs { const float* wih[4]; const float* bih[4]; const float* bhh[4]; };

// ---------------- weight repack + bias fold ----------------
__global__ __launch_bounds__(64) void k_prepw(PrepArgs pa) {
    int r = blockIdx.x;                 // 0..1535
    int pq = r / 768, col = r % 768;
    int dir = col / 384, within = col % 384, gate = within / 128;
    int idx = pq * 2 + dir;             // {p_f,p_b,q_f,q_b}
    const float* wsrc = pa.wih[idx] + within * E_;
    __hip_bfloat16* dst = pq ? g_wq[col] : g_wp[col];
    for (int c = threadIdx.x; c < KP; c += 64)
        dst[c] = __float2bfloat16(c < E_ ? wsrc[c] : 0.f);
    if (threadIdx.x == 0) {
        float bsum = pa.bih[idx][within] + (gate < 2 ? pa.bhh[idx][within] : 0.f);
        (pq ? g_biasq : g_biasp)[col] = bsum;
        if (within >= 256) g_biasn[idx][within - 256] = pa.bhh[idx][within];
    }
}

// ---------------- whh -> MFMA B-fragment repack (bf16) ----------------
__global__ __launch_bounds__(512) void k_prepw2(const float* w0, const float* w1,
                                               const float* w2, const float* w3) {
    int widx = blockIdx.x;              // 0..3
    const float* whh = widx == 0 ? w0 : widx == 1 ? w1 : widx == 2 ? w2 : w3;
    int tid = threadIdx.x, l = tid & 63, w = tid >> 6;
    int l15 = l & 15, lg = l >> 4;
    int j = w * 16 + l15;
    #pragma unroll
    for (int f = 0; f < 12; f++) {
        int g = f >> 2, ks = f & 3;
        const float* src = whh + (long)(g * 128 + j) * HH_ + ks * 32 + lg * 8;
        bf16x8 v;
        #pragma unroll
        for (int e = 0; e < 8; e++) {
            unsigned u = __float_as_uint(src[e]);
            u = (u + 0x7FFFu + ((u >> 16) & 1u)) >> 16;   // RNE f32->bf16
            v[e] = (short)u;
        }
        ((bf16x8*)g_whhrep)[(widx * 12 + f) * 512 + tid] = v;
    }
}

// ---------------- embedding gather (f32 -> bf16, K padded) ----------------
__global__ __launch_bounds__(256) void k_gather(const int* pass, const int* ques, const float* emb) {
    int row = blockIdx.x * 4 + (threadIdx.x >> 6);
    int lane = threadIdx.x & 63;
    const int* tsrc; __hip_bfloat16* dst; int r;
    if (row < BP) { r = row; tsrc = pass; dst = &g_ep[r][0]; }
    else          { r = row - BP; tsrc = ques; dst = &g_eq[r][0]; }
    int tk = tsrc[r];
    const float* src = emb + (long)tk * E_;
    #pragma unroll
    for (int i = 0; i < 5; i++) {
        int c = i * 64 + lane;
        float v = (c < E_) ? src[c] : 0.f;
        dst[c] = __float2bfloat16(v);
    }
}

// ---------------- input-projection GEMM: x_t[dir][t][b][384] = ep @ wih^T + bias ----------------
__global__ __launch_bounds__(256) void k_gemm(int isQ) {
    const __hip_bfloat16* A  = isQ ? &g_eq[0][0] : &g_ep[0][0];
    const __hip_bfloat16* Bw = isQ ? &g_wq[0][0] : &g_wp[0][0];
    const float* bias = isQ ? g_biasq : g_biasp;
    float* Xt = isQ ? g_xtq : g_xtp;
    const int T = isQ ? Q_ : P_;
    const int tsh = isQ ? 6 : 9;        // log2(T)
    __shared__ __hip_bfloat16 As[128][40];
    __shared__ __hip_bfloat16 Bs[128][40];
    int m0 = blockIdx.x * 128, n0 = blockIdx.y * 128;
    int tid = threadIdx.x, lane = tid & 63, w = tid >> 6;
    int wm = (w & 1) * 64, wn = (w >> 1) * 64;
    f32x4 acc[4][4] = {};
    int lr = tid >> 1, lc = (tid & 1) * 16;
    for (int kt = 0; kt < KP; kt += 32) {
        *(bf16x8*)&As[lr][lc]   = *(const bf16x8*)&A [(m0 + lr) * KP + kt + lc];
        *(bf16x8*)&As[lr][lc+8] = *(const bf16x8*)&A [(m0 + lr) * KP + kt + lc + 8];
        *(bf16x8*)&Bs[lr][lc]   = *(const bf16x8*)&Bw[(n0 + lr) * KP + kt + lc];
        *(bf16x8*)&Bs[lr][lc+8] = *(const bf16x8*)&Bw[(n0 + lr) * KP + kt + lc + 8];
        __syncthreads();
        int kb = (lane >> 4) * 8, l15 = lane & 15;
        bf16x8 af[4], bfr[4];
        #pragma unroll
        for (int i = 0; i < 4; i++) af[i]  = *(bf16x8*)&As[wm + i*16 + l15][kb];
        #pragma unroll
        for (int j = 0; j < 4; j++) bfr[j] = *(bf16x8*)&Bs[wn + j*16 + l15][kb];
        #pragma unroll
        for (int i = 0; i < 4; i++)
            #pragma unroll
            for (int j = 0; j < 4; j++)
                acc[i][j] = __builtin_amdgcn_mfma_f32_16x16x32_bf16(af[i], bfr[j], acc[i][j], 0, 0, 0);
        __syncthreads();
    }
    int l15 = lane & 15, lr4 = (lane >> 4) * 4;
    #pragma unroll
    for (int jj = 0; jj < 4; jj++) {
        int n = n0 + wn + jj * 16 + l15;
        float bn = bias[n];
        int dirn = n >= 384;
        int col = n - dirn * 384;
        float* Cx = Xt + (long)dirn * T * B_ * 384;
        #pragma unroll
        for (int i = 0; i < 4; i++) {
            int mb = m0 + wm + i * 16 + lr4;
            #pragma unroll
            for (int q = 0; q < 4; q++) {
                int m = mb + q;
                int b = m >> tsh, t = m & (T - 1);
                Cx[((long)t * B_ + b) * 384 + col] = acc[i][jj][q] + bn;
            }
        }
    }
}

// ---------------- z-gate poison for masked steps (freeze h exactly) ----------------
__global__ __launch_bounds__(128) void k_maskz(const int* pass, const int* ques) {
    int row = blockIdx.x;
    int tid = threadIdx.x;
    int isQ = row >= BP;
    int rr = isQ ? row - BP : row;
    int tkn = isQ ? ques[rr] : pass[rr];
    if (tkn != 0) return;
    int T = isQ ? Q_ : P_;
    int b = rr / T, t = rr % T;
    float* xt = isQ ? g_xtq : g_xtp;
    xt[((long)0 * T * B_ + (long)t * B_ + b) * 384 + 128 + tid] = 1e9f;
    xt[((long)1 * T * B_ + (long)t * B_ + b) * 384 + 128 + tid] = 1e9f;
}

// ---------------- GRU recurrence: MFMA over 16 chains per block ----------------
// 8 blocks x 512 threads. A = h[16][128] (chains x hidden), B = whh fragments
// resident as 12 named bf16x8 scalars. No token loads (z-poison handles masking).
__global__ __launch_bounds__(512, 1) void k_gru() {
    int blk = blockIdx.x;               // 0..7
    int isQ = blk >> 2, dir = (blk >> 1) & 1, bbase = (blk & 1) * 16;
    const int T = isQ ? Q_ : P_;
    const float* xt = (isQ ? g_xtq : g_xtp) + (long)dir * T * B_ * 384;
    float* outp = isQ ? g_qenc : g_penc;
    int widx = isQ * 2 + dir;
    int tid = threadIdx.x, l = tid & 63, w = tid >> 6;
    int l15 = l & 15, lg = l >> 4;
    int j = w * 16 + l15, m0 = lg * 4;

    const bf16x8* wrp = (const bf16x8*)g_whhrep + (long)widx * 12 * 512 + tid;
    bf16x8 b00 = wrp[0*512],  b01 = wrp[1*512],  b02 = wrp[2*512],  b03 = wrp[3*512];
    bf16x8 b10 = wrp[4*512],  b11 = wrp[5*512],  b12 = wrp[6*512],  b13 = wrp[7*512];
    bf16x8 b20 = wrp[8*512],  b21 = wrp[9*512],  b22 = wrp[10*512], b23 = wrp[11*512];
    float bnn = g_biasn[widx][j];

    __shared__ __align__(16) char hb[2][4096];   // h as bf16 [16][128], swizzled, dbuf

    f32x4 hold = {0.f, 0.f, 0.f, 0.f};
    bf16x8 af0 = {0,0,0,0,0,0,0,0};
    bf16x8 af1 = af0, af2 = af0, af3 = af0;

    long rowoff = (long)(bbase + m0) * 384 + j;
    f32x4 xar, xaz, xan;
    {
        int t0 = dir ? T - 1 : 0;
        const float* xr = xt + (long)t0 * (B_ * 384) + rowoff;
        #pragma unroll
        for (int q = 0; q < 4; q++) {
            xar[q] = xr[q * 384];
            xaz[q] = xr[q * 384 + 128];
            xan[q] = xr[q * 384 + 256];
        }
    }
    int cur = 0;
    for (int st = 0; st < T; st++) {
        int t = dir ? T - 1 - st : st;
        int s1 = (st + 1 < T) ? st + 1 : st;
        int t1 = dir ? T - 1 - s1 : s1;
        // prefetch next-step x (consumed next iteration -> full step of slack)
        f32x4 xbr, xbz, xbn;
        {
            const float* xr = xt + (long)t1 * (B_ * 384) + rowoff;
            #pragma unroll
            for (int q = 0; q < 4; q++) {
                xbr[q] = xr[q * 384];
                xbz[q] = xr[q * 384 + 128];
                xbn[q] = xr[q * 384 + 256];
            }
        }
        f32x4 acc0 = {0.f,0.f,0.f,0.f}, acc1 = acc0, acc2 = acc0;
        acc0 = __builtin_amdgcn_mfma_f32_16x16x32_bf16(af0, b00, acc0, 0, 0, 0);
        acc1 = __builtin_amdgcn_mfma_f32_16x16x32_bf16(af0, b10, acc1, 0, 0, 0);
        acc2 = __builtin_amdgcn_mfma_f32_16x16x32_bf16(af0, b20, acc2, 0, 0, 0);
        acc0 = __builtin_amdgcn_mfma_f32_16x16x32_bf16(af1, b01, acc0, 0, 0, 0);
        acc1 = __builtin_amdgcn_mfma_f32_16x16x32_bf16(af1, b11, acc1, 0, 0, 0);
        acc2 = __builtin_amdgcn_mfma_f32_16x16x32_bf16(af1, b21, acc2, 0, 0, 0);
        acc0 = __builtin_amdgcn_mfma_f32_16x16x32_bf16(af2, b02, acc0, 0, 0, 0);
        acc1 = __builtin_amdgcn_mfma_f32_16x16x32_bf16(af2, b12, acc1, 0, 0, 0);
        acc2 = __builtin_amdgcn_mfma_f32_16x16x32_bf16(af2, b22, acc2, 0, 0, 0);
        acc0 = __builtin_amdgcn_mfma_f32_16x16x32_bf16(af3, b03, acc0, 0, 0, 0);
        acc1 = __builtin_amdgcn_mfma_f32_16x16x32_bf16(af3, b13, acc1, 0, 0, 0);
        acc2 = __builtin_amdgcn_mfma_f32_16x16x32_bf16(af3, b23, acc2, 0, 0, 0);
        // gates (masked steps: xaz=1e9 -> z=1 -> hnew == hold exactly)
        f32x4 hnew;
        #pragma unroll
        for (int q = 0; q < 4; q++) {
            float rg = 1.f / (1.f + __expf(-(acc0[q] + xar[q])));
            float zg = 1.f / (1.f + __expf(-(acc1[q] + xaz[q])));
            float ta = xan[q] + rg * (acc2[q] + bnn);
            ta = fminf(fmaxf(ta, -15.f), 15.f);
            float e2 = __expf(2.f * ta);
            float nn = 1.f - 2.f / (e2 + 1.f);
            hnew[q] = (1.f - zg) * nn + zg * hold[q];
        }
        hold = hnew;
        {
            float* orow = outp + ((long)(bbase + m0) * T + t) * H_ + dir * HH_ + j;
            #pragma unroll
            for (int q = 0; q < 4; q++)
                orow[(long)q * T * H_] = hnew[q];
        }
        // h exchange via swizzled LDS (dbuf, one barrier per step)
        char* wb = hb[cur];
        #pragma unroll
        for (int q = 0; q < 4; q++) {
            int m = m0 + q;
            *(__hip_bfloat16*)(wb + m * 256 + ((j * 2) ^ ((m & 7) << 4))) = __float2bfloat16(hnew[q]);
        }
        __syncthreads();
        const char* rb = hb[cur];
        af0 = *(const bf16x8*)(rb + l15 * 256 + ((0 * 64 + lg * 16) ^ ((l15 & 7) << 4)));
        af1 = *(const bf16x8*)(rb + l15 * 256 + ((1 * 64 + lg * 16) ^ ((l15 & 7) << 4)));
        af2 = *(const bf16x8*)(rb + l15 * 256 + ((2 * 64 + lg * 16) ^ ((l15 & 7) << 4)));
        af3 = *(const bf16x8*)(rb + l15 * 256 + ((3 * 64 + lg * 16) ^ ((l15 & 7) << 4)));
        cur ^= 1;
        xar = xbr; xaz = xbz; xan = xbn;
    }
}

// ---------------- fused attention + output heads ----------------
#define QPAD 260
__global__ __launch_bounds__(256) void k_attn(const int* pass, const int* ques,
        const float* attn_w, const float* attn_b, const float* start_w,
        const float* start_b, const float* end_w, const float* end_b, float* out) {
    __shared__ float qs[Q_][QPAD];
    __shared__ float pw3[H_];
    __shared__ float lrow[Q_];
    __shared__ float probs[Q_];
    __shared__ float s2v[Q_];
    __shared__ int   qmS[Q_];
    __shared__ float red[4], redA[4], redB[4];
    __shared__ float awpart[4][QPAD];
    int b = blockIdx.x >> 6, pch = blockIdx.x & 63;
    int tid = threadIdx.x, lane = tid & 63, wid = tid >> 6;
    for (int i = tid; i < Q_ * H_; i += 256) {
        int q = i >> 8, h = i & 255;
        qs[q][h] = g_qenc[(long)(b * Q_ + q) * H_ + h];
    }
    if (tid < Q_) qmS[tid] = (ques[b * Q_ + tid] != 0);
    __syncthreads();
    int q4 = tid >> 2, part = tid & 3;
    {   // s2[q] = dot(qenc[q], w2)
        float p2 = 0.f;
        #pragma unroll 8
        for (int i = 0; i < 64; i++)
            p2 += qs[q4][part * 64 + i] * attn_w[256 + part * 64 + i];
        p2 += __shfl_xor(p2, 1);
        p2 += __shfl_xor(p2, 2);
        if (part == 0) s2v[q4] = p2;
    }
    __syncthreads();
    float ab = attn_b[0], sb = start_b[0], ebv = end_b[0];
    for (int pi = 0; pi < 8; pi++) {
        int p = pch * 8 + pi;
        float pv = g_penc[(long)(b * P_ + p) * H_ + tid];
        pw3[tid] = pv * attn_w[512 + tid];
        float r1 = pv * attn_w[tid];
        #pragma unroll
        for (int s = 1; s < 64; s <<= 1) r1 += __shfl_xor(r1, s);
        if (lane == 0) red[wid] = r1;
        __syncthreads();                                  // (A) pw3 + red
        float s1 = red[0] + red[1] + red[2] + red[3];
        float acc = 0.f;
        #pragma unroll
        for (int i = 0; i < 16; i++) {
            float4 qv = *(const float4*)&qs[q4][part * 64 + i * 4];
            float4 wv = *(const float4*)&pw3[part * 64 + i * 4];
            acc += qv.x * wv.x + qv.y * wv.y + qv.z * wv.z + qv.w * wv.w;
        }
        acc += __shfl_xor(acc, 1);
        acc += __shfl_xor(acc, 2);
        if (part == 0) lrow[q4] = qmS[q4] ? (s1 + s2v[q4] + acc + ab) : NEG;
        __syncthreads();                                  // (B) lrow
        if (tid < 64) {
            float v = lrow[tid];
            float m = v;
            #pragma unroll
            for (int s = 1; s < 64; s <<= 1) m = fmaxf(m, __shfl_xor(m, s));
            float e = __expf(v - m);
            float ss = e;
            #pragma unroll
            for (int s = 1; s < 64; s <<= 1) ss += __shfl_xor(ss, s);
            probs[tid] = e / ss;
        }
        __syncthreads();                                  // (C) probs
        float4 aw4 = {0.f, 0.f, 0.f, 0.f};
        #pragma unroll
        for (int qq = 0; qq < 16; qq++) {
            int q = wid * 16 + qq;
            float pq = probs[q];
            float4 qv = *(const float4*)&qs[q][lane * 4];
            aw4.x = fmaf(pq, qv.x, aw4.x);
            aw4.y = fmaf(pq, qv.y, aw4.y);
            aw4.z = fmaf(pq, qv.z, aw4.z);
            aw4.w = fmaf(pq, qv.w, aw4.w);
        }
        *(float4*)&awpart[wid][lane * 4] = aw4;
        __syncthreads();                                  // (D0) awpart
        float aw = awpart[0][tid] + awpart[1][tid] + awpart[2][tid] + awpart[3][tid];
        float spv = pv * start_w[tid] + aw * start_w[256 + tid] + pv * aw * start_w[512 + tid];
        float epv = pv * end_w[tid]   + aw * end_w[256 + tid]   + pv * aw * end_w[512 + tid];
        #pragma unroll
        for (int s = 1; s < 64; s <<= 1) {
            spv += __shfl_xor(spv, s);
            epv += __shfl_xor(epv, s);
        }
        if (lane == 0) { redA[wid] = spv; redB[wid] = epv; }
        __syncthreads();                                  // (D) redA/B
        if (tid == 0) {
            int pm = (pass[b * P_ + p] != 0);
            float sv = redA[0] + redA[1] + redA[2] + redA[3] + sb;
            float ev = redB[0] + redB[1] + redB[2] + redB[3] + ebv;
            out[b * P_ + p]       = pm ? sv : NEG;
            out[BP + b * P_ + p]  = pm ? ev : NEG;
        }
        __syncthreads();                                  // (E) end of row
    }
}

// ---------------- log_softmax over P per (batch, start/end) ----------------
__global__ __launch_bounds__(256) void k_lsm(float* out) {
    int b = blockIdx.x >> 1, which = blockIdx.x & 1;
    const float* src = out + which * BP + b * P_;
    int tid = threadIdx.x;
    float v0 = src[tid], v1 = src[tid + 256];
    __shared__ float red[4];
    float m = fmaxf(v0, v1);
    #pragma unroll
    for (int s = 1; s < 64; s <<= 1) m = fmaxf(m, __shfl_xor(m, s));
    if ((tid & 63) == 0) red[tid >> 6] = m;
    __syncthreads();
    m = fmaxf(fmaxf(red[0], red[1]), fmaxf(red[2], red[3]));
    __syncthreads();
    float ss = __expf(v0 - m) + __expf(v1 - m);
    #pragma unroll
    for (int s = 1; s < 64; s <<= 1) ss += __shfl_xor(ss, s);
    if ((tid & 63) == 0) red[tid >> 6] = ss;
    __syncthreads();
    float lse = m + logf(red[0] + red[1] + red[2] + red[3]);
    float* dst = out + (2 + which) * BP + b * P_;
    dst[tid] = v0 - lse;
    dst[tid + 256] = v1 - lse;
}

extern "C" void kernel_launch(void* const* d_in, const int* in_sizes, int n_in,
                              void* d_out, int out_size, void* d_ws, size_t ws_size,
                              hipStream_t stream) {
    const int* pass = (const int*)d_in[0];
    const int* ques = (const int*)d_in[1];
    const float* emb = (const float*)d_in[2];
    PrepArgs pa;
    const float* whh[4];
    const int base[4] = {3, 7, 11, 15};   // p_f, p_b, q_f, q_b blocks of 4 inputs
    for (int i = 0; i < 4; i++) {
        pa.wih[i] = (const float*)d_in[base[i] + 0];
        whh[i]    = (const float*)d_in[base[i] + 1];
        pa.bih[i] = (const float*)d_in[base[i] + 2];
        pa.bhh[i] = (const float*)d_in[base[i] + 3];
    }
    const float* attn_w  = (const float*)d_in[19];
    const float* attn_b  = (const float*)d_in[20];
    const float* start_w = (const float*)d_in[21];
    const float* start_b = (const float*)d_in[22];
    const float* end_w   = (const float*)d_in[23];
    const float* end_b   = (const float*)d_in[24];
    float* out = (float*)d_out;

    k_prepw <<<dim3(1536), dim3(64), 0, stream>>>(pa);
    k_prepw2<<<dim3(4), dim3(512), 0, stream>>>(whh[0], whh[1], whh[2], whh[3]);
    k_gather<<<dim3((BP + BQ) / 4), dim3(256), 0, stream>>>(pass, ques, emb);
    k_gemm  <<<dim3(BP / 128, 6), dim3(256), 0, stream>>>(0);
    k_gemm  <<<dim3(BQ / 128, 6), dim3(256), 0, stream>>>(1);
    k_maskz <<<dim3(BP + BQ), dim3(128), 0, stream>>>(pass, ques);
    k_gru   <<<dim3(8), dim3(512), 0, stream>>>();
    k_attn  <<<dim3(B_ * 64), dim3(256), 0, stream>>>(pass, ques, attn_w, attn_b,
                                                      start_w, start_b, end_w, end_b, out);
    k_lsm   <<<dim3(64), dim3(256), 0, stream>>>(out);
}